// Round 10
// baseline (115.348 us; speedup 1.0000x reference)
//
#include <hip/hip_runtime.h>
#include <math.h>

typedef unsigned short u16;
typedef unsigned int u32;
typedef unsigned long long u64;
typedef __bf16 bf16x8 __attribute__((ext_vector_type(8)));
typedef short s16x4 __attribute__((ext_vector_type(4)));
typedef float f32x4 __attribute__((ext_vector_type(4)));

#define SCALING 0.17677669529663687f   // 32^-0.5
#define LOG2E 1.44269504088896f
#define LOG2_10000 13.287712379549449f

__device__ __forceinline__ u16 f2bf(float f) {
    u32 u; __builtin_memcpy(&u, &f, 4);
    u = u + 0x7FFFu + ((u >> 16) & 1u);
    return (u16)(u >> 16);
}
__device__ __forceinline__ u32 fbits(float f) {
    u32 u; __builtin_memcpy(&u, &f, 4); return u;
}
// pack two f32 -> (bf16(lo) | bf16(hi)<<16)
__device__ __forceinline__ u32 pack_bf16(float lo, float hi) {
#if __has_builtin(__builtin_amdgcn_cvt_pk_bf16_f32)
    typedef __bf16 bf16x2_t __attribute__((ext_vector_type(2)));
    bf16x2_t r = __builtin_amdgcn_cvt_pk_bf16_f32(lo, hi);
    u32 u; __builtin_memcpy(&u, &r, 4); return u;
#else
    return __builtin_amdgcn_perm(fbits(hi) + 0x8000u, fbits(lo) + 0x8000u, 0x07060302u);
#endif
}
__device__ __forceinline__ f32x4 mfma16(bf16x8 a, bf16x8 b, f32x4 c) {
    return __builtin_amdgcn_mfma_f32_16x16x32_bf16(a, b, c, 0, 0, 0);
}
// K=16 bf16 MFMA: 4 bf16 per lane per operand (2 VGPRs)
__device__ __forceinline__ f32x4 mfma_k16(u64 a, u64 b, f32x4 c) {
#if __has_builtin(__builtin_amdgcn_mfma_f32_16x16x16bf16_1k)
    s16x4 av, bv;
    __builtin_memcpy(&av, &a, 8); __builtin_memcpy(&bv, &b, 8);
    return __builtin_amdgcn_mfma_f32_16x16x16bf16_1k(av, bv, c, 0, 0, 0);
#elif __has_builtin(__builtin_amdgcn_mfma_f32_16x16x16_bf16)
    typedef __bf16 bf16x4_t __attribute__((ext_vector_type(4)));
    bf16x4_t av, bv;
    __builtin_memcpy(&av, &a, 8); __builtin_memcpy(&bv, &b, 8);
    return __builtin_amdgcn_mfma_f32_16x16x16_bf16(av, bv, c, 0, 0, 0);
#else
    f32x4 d = c;
    asm volatile("v_mfma_f32_16x16x16_bf16 %0, %1, %2, %0\n\ts_nop 4"
                 : "+v"(d) : "v"(a), "v"(b));
    return d;
#endif
}
__device__ __forceinline__ float decay_l2(int h) {
    return logf(1.0f - exp2f(-2.0f - 0.625f * (float)h)) * LOG2E;
}

// ---- prep: x->bf16 (1024 blk), W->bf16 (128 blk), theta table (128 blk) ------
__global__ __launch_bounds__(256) void prep_kernel(
    const float* __restrict__ x,
    const float* __restrict__ Wq, const float* __restrict__ Wk,
    const float* __restrict__ Wv, const float* __restrict__ Wo,
    u16* __restrict__ xb, u16* __restrict__ wb, float2* __restrict__ tc) {
    int bid = blockIdx.x;
    if (bid >= 1152) {   // tc[l*32+d] = (cos, d odd? sin : -sin)
        int idx = (bid - 1152) * 256 + threadIdx.x;   // 0..32767
        int l = idx >> 5, d = idx & 31;
        float ang = exp2f(-LOG2_10000 * (1.0f / 15.0f) * (float)(d >> 1));
        float idl = (float)((l >> 5) + (l & 31));
        float sv, cv;
        __sincosf(idl * ang, &sv, &cv);
        tc[idx] = make_float2(cv, (d & 1) ? sv : -sv);
        return;
    }
    const float* src; u16* dst; int off;
    if (bid < 1024) { src = x; dst = xb; off = bid * 2048; }
    else {
        int wsel = (bid - 1024) >> 5;
        src = (wsel == 0) ? Wq : (wsel == 1) ? Wk : (wsel == 2) ? Wv : Wo;
        dst = wb + wsel * 65536;
        off = ((bid - 1024) & 31) * 2048;
    }
    int i = off + threadIdx.x * 8;
    float4 a = *(const float4*)&src[i];
    float4 b = *(const float4*)&src[i + 4];
    int4 t;
    t.x = (int)pack_bf16(a.x, a.y); t.y = (int)pack_bf16(a.z, a.w);
    t.z = (int)pack_bf16(b.x, b.y); t.w = (int)pack_bf16(b.z, b.w);
    *(int4*)&dst[i] = t;
}

// ------- GEMM C[i][e] = sum_j A[i][j] W[e][j], MT m-frags per wave ------------
// modes: 0=q (theta-shift), 1=k (scale+shift), 2=v, 3=plain f32 out
template<int MT>
__global__ __launch_bounds__(256) void gemm_bt_kernel(
    const u16* __restrict__ A, const u16* __restrict__ Wb,
    const float2* __restrict__ tc,
    u16* __restrict__ O0, u16* __restrict__ O1, u16* __restrict__ O2,
    float* __restrict__ Of, int mode_base) {
    __shared__ __align__(16) u16 As[64 * MT * 136];
    __shared__ __align__(16) u16 Ws[64 * 136];
    int z = blockIdx.z;
    const u16* W = Wb + z * 65536;
    u16* O = (z == 0) ? O0 : (z == 1) ? O1 : O2;
    int mode = mode_base + z;
    int n0 = blockIdx.x * 64, r0 = blockIdx.y * (64 * MT);
    int tid = threadIdx.x;
    int w = tid >> 6, lane = tid & 63, ln = lane & 15, quad = lane >> 4;
    f32x4 acc[MT][4] = {};
#pragma unroll
    for (int ch = 0; ch < 2; ch++) {
        int k0 = ch * 128;
        if (ch) __syncthreads();
#pragma unroll
        for (int i = 0; i < 4 * MT; i++) {
            int c = tid + i * 256;
            int row = c >> 4, seg = c & 15;
            *(int4*)&As[row * 136 + seg * 8] = *(const int4*)&A[(long)(r0 + row) * 256 + k0 + seg * 8];
        }
#pragma unroll
        for (int i = 0; i < 4; i++) {
            int c = tid + i * 256;
            int row = c >> 4, seg = c & 15;
            *(int4*)&Ws[row * 136 + seg * 8] = *(const int4*)&W[(long)(n0 + row) * 256 + k0 + seg * 8];
        }
        __syncthreads();
#pragma unroll
        for (int kt = 0; kt < 4; kt++) {
            bf16x8 a[MT];
#pragma unroll
            for (int m = 0; m < MT; m++)
                a[m] = *(const bf16x8*)&As[(w * MT * 16 + m * 16 + ln) * 136 + kt * 32 + quad * 8];
#pragma unroll
            for (int nt = 0; nt < 4; nt++) {
                bf16x8 b = *(const bf16x8*)&Ws[(nt * 16 + ln) * 136 + kt * 32 + quad * 8];
#pragma unroll
                for (int m = 0; m < MT; m++)
                    acc[m][nt] = mfma16(a[m], b, acc[m][nt]);
            }
        }
    }
#pragma unroll
    for (int m = 0; m < MT; m++) {
        int rowg = r0 + w * MT * 16 + m * 16 + quad * 4;   // C row = quad*4 + reg
        if (mode == 3) {
#pragma unroll
            for (int nt = 0; nt < 4; nt++) {
                int e = n0 + nt * 16 + ln;
#pragma unroll
                for (int r = 0; r < 4; r++)
                    Of[(long)(rowg + r) * 256 + e] = acc[m][nt][r];
            }
            continue;
        }
        float scl = (mode == 1) ? SCALING : 1.0f;
#pragma unroll
        for (int nt = 0; nt < 4; nt++) {
            int e = n0 + nt * 16 + ln;
            int d = e & 31, hh = e >> 5;
#pragma unroll
            for (int r = 0; r < 4; r++) {
                int gi = rowg + r;
                int b = gi >> 10, l = gi & 1023;
                float v = acc[m][nt][r] * scl;
                float p = __shfl_xor(v, 1);   // partner col e^1, same row
                float res;
                if (mode == 2) {
                    res = v;
                } else {
                    float2 sc = tc[l * 32 + d];
                    res = v * sc.x + p * sc.y;
                }
                O[(((long)(b * 8 + hh)) * 1024 + l) * 32 + d] = f2bf(res);
            }
        }
    }
}

// ---- fused retention + LN + GELU: 128-q tile, 8 waves, register-P K=16 PV ----
// (byte-identical to the R8 kernel that passed at 113.5 us)
__global__ __launch_bounds__(512) void attn_kernel(
    const u16* __restrict__ qr, const u16* __restrict__ kr, const u16* __restrict__ vr,
    const float* __restrict__ lng, const float* __restrict__ lnb,
    u16* __restrict__ out) {
    __shared__ __align__(16) u16 Qs[128 * 40];      // 10240 B
    __shared__ __align__(16) u16 Ks[2][64 * 40];    // 10240 B
    __shared__ __align__(16) u32 VtW[2][32 * 36];   // V^T packed dwords, 9216 B
    __shared__ float Tt[64];
    __shared__ float Ss[32];
    int b = blockIdx.z, h = blockIdx.y, q0 = blockIdx.x * 128;
    int tid = threadIdx.x, w = tid >> 6, lane = tid & 63, ln = lane & 15, quad = lane >> 4;
    long bh = b * 8 + h;
    const u16* qb = qr + bh * 32768;
    const u16* kb = kr + bh * 32768;
    const u16* vb = vr + bh * 32768;
    float dec = decay_l2(h);
    {   // stage Q (128 rows, 512 threads)
        int row = tid >> 2, seg = tid & 3;
        *(int4*)&Qs[row * 40 + seg * 8] = *(const int4*)&qb[(q0 + row) * 32 + seg * 8];
    }
    if (tid < 63) Tt[tid] = exp2f(dec * (float)tid);
    // staging duties: waves 0-3 stage K, waves 4-7 stage V
    bool isK = (tid < 256);
    int krow = (tid & 255) >> 2, kseg = tid & 3;
    int vt = tid & 255, vp = vt >> 3, vseg = vt & 7;
    int4 kreg; int2 v0, v1;
    if (isK) {
        kreg = *(const int4*)&kb[(long)krow * 32 + kseg * 8];
    } else {
        v0 = *(const int2*)&vb[(long)(vp * 2) * 32 + vseg * 4];
        v1 = *(const int2*)&vb[(long)(vp * 2 + 1) * 32 + vseg * 4];
    }
    __syncthreads();   // Qs + Tt ready
    bf16x8 aq = *(const bf16x8*)&Qs[(w * 16 + ln) * 40 + quad * 8];   // Q B-frag
    int q = q0 + w * 16 + ln;
    int q1i = q >> 5, q2i = q & 31;
    if (tid < 32) {
        float s = 0.0f;
#pragma unroll
        for (int b2 = 0; b2 < 32; b2++) s += Tt[abs(tid - b2)];
        Ss[tid] = s;
    }
    // write tile 0 to buf 0, prefetch tile 1
    if (isK) {
        *(int4*)&Ks[0][krow * 40 + kseg * 8] = kreg;
        kreg = *(const int4*)&kb[(long)(64 + krow) * 32 + kseg * 8];
    } else {
        VtW[0][(vseg * 4 + 0) * 36 + vp] = __builtin_amdgcn_perm(v1.x, v0.x, 0x05040100u);
        VtW[0][(vseg * 4 + 1) * 36 + vp] = __builtin_amdgcn_perm(v1.x, v0.x, 0x07060302u);
        VtW[0][(vseg * 4 + 2) * 36 + vp] = __builtin_amdgcn_perm(v1.y, v0.y, 0x05040100u);
        VtW[0][(vseg * 4 + 3) * 36 + vp] = __builtin_amdgcn_perm(v1.y, v0.y, 0x07060302u);
        v0 = *(const int2*)&vb[(long)(64 + vp * 2) * 32 + vseg * 4];
        v1 = *(const int2*)&vb[(long)(64 + vp * 2 + 1) * 32 + vseg * 4];
    }
    __syncthreads();   // Ss + buf0 ready
    float rqv = rsqrtf(Ss[q1i] * Ss[q2i]);
    float bt[2][4];
#pragma unroll
    for (int s2 = 0; s2 < 2; s2++)
#pragma unroll
        for (int r = 0; r < 4; r++)
            bt[s2][r] = Tt[abs(q2i - (s2 * 16 + quad * 4 + r))] * rqv;   // rqv folded
    f32x4 accO0 = {}, accO1 = {};
    float den = 0.0f;
    for (int kt = 0; kt < 16; kt++) {
        int cur = kt & 1;
        float a0 = Tt[abs(q1i - 2 * kt)];
        float a1 = Tt[abs(q1i - 2 * kt - 1)];
        const u16* ksb = &Ks[cur][0];
        const u32* vtb = &VtW[cur][0];
#pragma unroll
        for (int nt = 0; nt < 4; nt++) {
            bf16x8 ak = *(const bf16x8*)&ksb[(nt * 16 + ln) * 40 + quad * 8];
            f32x4 s = mfma16(ak, aq, (f32x4){0.f, 0.f, 0.f, 0.f});   // S^T rows kk, col q
            float aa = (nt & 2) ? a1 : a0;
            float p0 = s[0] * aa * bt[nt & 1][0];
            float p1 = s[1] * aa * bt[nt & 1][1];
            float p2 = s[2] * aa * bt[nt & 1][2];
            float p3 = s[3] * aa * bt[nt & 1][3];
            den += fabsf(p0); den += fabsf(p1); den += fabsf(p2); den += fabsf(p3);
            // P^T fragment stays in registers: B-frag of K=16 MFMA = C-layout
            u32 blo = pack_bf16(p0, p1), bhi = pack_bf16(p2, p3);
            u64 bb = ((u64)bhi << 32) | blo;
            u64 av0 = *(const u64*)&vtb[ln * 36 + nt * 8 + quad * 2];
            u64 av1 = *(const u64*)&vtb[(16 + ln) * 36 + nt * 8 + quad * 2];
            accO0 = mfma_k16(av0, bb, accO0);   // O^T rows d=quad*4+r, col q
            accO1 = mfma_k16(av1, bb, accO1);   // d = 16 + quad*4+r
        }
        if (kt < 15) {
            int nb = 1 - cur;
            if (isK) {
                *(int4*)&Ks[nb][krow * 40 + kseg * 8] = kreg;
                if (kt < 14)
                    kreg = *(const int4*)&kb[(long)((kt + 2) * 64 + krow) * 32 + kseg * 8];
            } else {
                VtW[nb][(vseg * 4 + 0) * 36 + vp] = __builtin_amdgcn_perm(v1.x, v0.x, 0x05040100u);
                VtW[nb][(vseg * 4 + 1) * 36 + vp] = __builtin_amdgcn_perm(v1.x, v0.x, 0x07060302u);
                VtW[nb][(vseg * 4 + 2) * 36 + vp] = __builtin_amdgcn_perm(v1.y, v0.y, 0x05040100u);
                VtW[nb][(vseg * 4 + 3) * 36 + vp] = __builtin_amdgcn_perm(v1.y, v0.y, 0x07060302u);
                if (kt < 14) {
                    int t2 = (kt + 2) * 64;
                    v0 = *(const int2*)&vb[(long)(t2 + vp * 2) * 32 + vseg * 4];
                    v1 = *(const int2*)&vb[(long)(t2 + vp * 2 + 1) * 32 + vseg * 4];
                }
            }
            __syncthreads();
        }
    }
    // reduce den over quads (lanes ln, 16+ln, 32+ln, 48+ln share col q)
    den += __shfl_xor(den, 16);
    den += __shfl_xor(den, 32);
    float id = 1.0f / fminf(fmaxf(den, 1.0f), 50000.0f);
    float o[8];
#pragma unroll
    for (int r = 0; r < 4; r++) { o[r] = accO0[r] * id; o[4 + r] = accO1[r] * id; }
    float s1 = 0.0f, s2 = 0.0f;
#pragma unroll
    for (int i = 0; i < 8; i++) { s1 += o[i]; s2 += o[i] * o[i]; }
    s1 += __shfl_xor(s1, 16); s1 += __shfl_xor(s1, 32);
    s2 += __shfl_xor(s2, 16); s2 += __shfl_xor(s2, 32);
    float mean = s1 * (1.0f / 32.0f);
    float var = s2 * (1.0f / 32.0f) - mean * mean;
    float rstd = rsqrtf(var + 1e-5f);
    float xg[8];
#pragma unroll
    for (int nv = 0; nv < 2; nv++)
#pragma unroll
        for (int r = 0; r < 4; r++) {
            int d = nv * 16 + quad * 4 + r;
            float xv = (o[nv * 4 + r] - mean) * rstd * lng[d] + lnb[d];
            xg[nv * 4 + r] = 0.5f * xv * (1.0f + erff(xv * 0.70710678118654752f));
        }
    u16* orow = out + ((long)(b * 1024 + q)) * 256 + h * 32;
    int2 st0, st1;
    st0.x = (int)pack_bf16(xg[0], xg[1]); st0.y = (int)pack_bf16(xg[2], xg[3]);
    st1.x = (int)pack_bf16(xg[4], xg[5]); st1.y = (int)pack_bf16(xg[6], xg[7]);
    *(int2*)&orow[quad * 4] = st0;
    *(int2*)&orow[16 + quad * 4] = st1;
}

extern "C" void kernel_launch(void* const* d_in, const int* in_sizes, int n_in,
                              void* d_out, int out_size, void* d_ws, size_t ws_size,
                              hipStream_t stream) {
    const float* x   = (const float*)d_in[0];
    const float* Wq  = (const float*)d_in[1];
    const float* Wk  = (const float*)d_in[2];
    const float* Wv  = (const float*)d_in[3];
    const float* Wo  = (const float*)d_in[4];
    const float* lng = (const float*)d_in[5];
    const float* lnb = (const float*)d_in[6];
    float* outp = (float*)d_out;

    u16* xb    = (u16*)d_ws;            // [B*L][256] bf16, 4 MB
    u16* wb    = xb + 2097152;          // Wq|Wk|Wv|Wo bf16, 0.5 MB
    u16* qr    = wb + 262144;           // [B][H][L][32] bf16, 4 MB
    u16* kr    = qr + 2097152;
    u16* vr    = kr + 2097152;
    u16* attnb = vr + 2097152;          // [B*L][256] bf16, 4 MB
    float2* tc = (float2*)(attnb + 2097152);   // [L][32], 256 KB

    prep_kernel<<<1280, 256, 0, stream>>>(x, Wq, Wk, Wv, Wo, xb, wb, tc);
    gemm_bt_kernel<2><<<dim3(4, 64, 3), 256, 0, stream>>>(xb, wb, tc, qr, kr, vr, nullptr, 0);
    attn_kernel<<<dim3(8, 8, 8), 512, 0, stream>>>(qr, kr, vr, lng, lnb, attnb);
    gemm_bt_kernel<1><<<dim3(4, 128, 1), 256, 0, stream>>>(attnb, wb + 3 * 65536, tc, nullptr, nullptr, nullptr, outp, 3);
}

// Round 11
// 112.594 us; speedup vs baseline: 1.0245x; 1.0245x over previous
//
#include <hip/hip_runtime.h>
#include <math.h>

typedef unsigned short u16;
typedef unsigned int u32;
typedef unsigned long long u64;
typedef __bf16 bf16x8 __attribute__((ext_vector_type(8)));
typedef short s16x4 __attribute__((ext_vector_type(4)));
typedef float f32x4 __attribute__((ext_vector_type(4)));

#define SCALING 0.17677669529663687f   // 32^-0.5
#define LOG2E 1.44269504088896f
#define LOG2_10000 13.287712379549449f

__device__ __forceinline__ u16 f2bf(float f) {
    u32 u; __builtin_memcpy(&u, &f, 4);
    u = u + 0x7FFFu + ((u >> 16) & 1u);
    return (u16)(u >> 16);
}
__device__ __forceinline__ u32 fbits(float f) {
    u32 u; __builtin_memcpy(&u, &f, 4); return u;
}
// pack two f32 -> (bf16(lo) | bf16(hi)<<16)
__device__ __forceinline__ u32 pack_bf16(float lo, float hi) {
#if __has_builtin(__builtin_amdgcn_cvt_pk_bf16_f32)
    typedef __bf16 bf16x2_t __attribute__((ext_vector_type(2)));
    bf16x2_t r = __builtin_amdgcn_cvt_pk_bf16_f32(lo, hi);
    u32 u; __builtin_memcpy(&u, &r, 4); return u;
#else
    return __builtin_amdgcn_perm(fbits(hi) + 0x8000u, fbits(lo) + 0x8000u, 0x07060302u);
#endif
}
__device__ __forceinline__ f32x4 mfma16(bf16x8 a, bf16x8 b, f32x4 c) {
    return __builtin_amdgcn_mfma_f32_16x16x32_bf16(a, b, c, 0, 0, 0);
}
// K=16 bf16 MFMA: 4 bf16 per lane per operand (2 VGPRs)
__device__ __forceinline__ f32x4 mfma_k16(u64 a, u64 b, f32x4 c) {
#if __has_builtin(__builtin_amdgcn_mfma_f32_16x16x16bf16_1k)
    s16x4 av, bv;
    __builtin_memcpy(&av, &a, 8); __builtin_memcpy(&bv, &b, 8);
    return __builtin_amdgcn_mfma_f32_16x16x16bf16_1k(av, bv, c, 0, 0, 0);
#elif __has_builtin(__builtin_amdgcn_mfma_f32_16x16x16_bf16)
    typedef __bf16 bf16x4_t __attribute__((ext_vector_type(4)));
    bf16x4_t av, bv;
    __builtin_memcpy(&av, &a, 8); __builtin_memcpy(&bv, &b, 8);
    return __builtin_amdgcn_mfma_f32_16x16x16_bf16(av, bv, c, 0, 0, 0);
#else
    f32x4 d = c;
    asm volatile("v_mfma_f32_16x16x16_bf16 %0, %1, %2, %0\n\ts_nop 4"
                 : "+v"(d) : "v"(a), "v"(b));
    return d;
#endif
}
__device__ __forceinline__ float decay_l2(int h) {
    return logf(1.0f - exp2f(-2.0f - 0.625f * (float)h)) * LOG2E;
}

// ---- prep: x->bf16 (1024 blk), W->bf16 (128 blk), theta table (128 blk) ------
__global__ __launch_bounds__(256) void prep_kernel(
    const float* __restrict__ x,
    const float* __restrict__ Wq, const float* __restrict__ Wk,
    const float* __restrict__ Wv, const float* __restrict__ Wo,
    u16* __restrict__ xb, u16* __restrict__ wb, float2* __restrict__ tc) {
    int bid = blockIdx.x;
    if (bid >= 1152) {   // tc[l*32+d] = (cos, d odd? sin : -sin)
        int idx = (bid - 1152) * 256 + threadIdx.x;   // 0..32767
        int l = idx >> 5, d = idx & 31;
        float ang = exp2f(-LOG2_10000 * (1.0f / 15.0f) * (float)(d >> 1));
        float idl = (float)((l >> 5) + (l & 31));
        float sv, cv;
        __sincosf(idl * ang, &sv, &cv);
        tc[idx] = make_float2(cv, (d & 1) ? sv : -sv);
        return;
    }
    const float* src; u16* dst; int off;
    if (bid < 1024) { src = x; dst = xb; off = bid * 2048; }
    else {
        int wsel = (bid - 1024) >> 5;
        src = (wsel == 0) ? Wq : (wsel == 1) ? Wk : (wsel == 2) ? Wv : Wo;
        dst = wb + wsel * 65536;
        off = ((bid - 1024) & 31) * 2048;
    }
    int i = off + threadIdx.x * 8;
    float4 a = *(const float4*)&src[i];
    float4 b = *(const float4*)&src[i + 4];
    int4 t;
    t.x = (int)pack_bf16(a.x, a.y); t.y = (int)pack_bf16(a.z, a.w);
    t.z = (int)pack_bf16(b.x, b.y); t.w = (int)pack_bf16(b.z, b.w);
    *(int4*)&dst[i] = t;
}

// ------- GEMM C[i][e] = sum_j A[i][j] W[e][j], MT m-frags per wave ------------
// modes: 0=q (theta-shift), 1=k (scale+shift), 2=v, 3=plain f32 out
template<int MT>
__global__ __launch_bounds__(256) void gemm_bt_kernel(
    const u16* __restrict__ A, const u16* __restrict__ Wb,
    const float2* __restrict__ tc,
    u16* __restrict__ O0, u16* __restrict__ O1, u16* __restrict__ O2,
    float* __restrict__ Of, int mode_base) {
    __shared__ __align__(16) u16 As[64 * MT * 136];
    __shared__ __align__(16) u16 Ws[64 * 136];
    int z = blockIdx.z;
    const u16* W = Wb + z * 65536;
    u16* O = (z == 0) ? O0 : (z == 1) ? O1 : O2;
    int mode = mode_base + z;
    int n0 = blockIdx.x * 64, r0 = blockIdx.y * (64 * MT);
    int tid = threadIdx.x;
    int w = tid >> 6, lane = tid & 63, ln = lane & 15, quad = lane >> 4;
    f32x4 acc[MT][4] = {};
#pragma unroll
    for (int ch = 0; ch < 2; ch++) {
        int k0 = ch * 128;
        if (ch) __syncthreads();
#pragma unroll
        for (int i = 0; i < 4 * MT; i++) {
            int c = tid + i * 256;
            int row = c >> 4, seg = c & 15;
            *(int4*)&As[row * 136 + seg * 8] = *(const int4*)&A[(long)(r0 + row) * 256 + k0 + seg * 8];
        }
#pragma unroll
        for (int i = 0; i < 4; i++) {
            int c = tid + i * 256;
            int row = c >> 4, seg = c & 15;
            *(int4*)&Ws[row * 136 + seg * 8] = *(const int4*)&W[(long)(n0 + row) * 256 + k0 + seg * 8];
        }
        __syncthreads();
#pragma unroll
        for (int kt = 0; kt < 4; kt++) {
            bf16x8 a[MT];
#pragma unroll
            for (int m = 0; m < MT; m++)
                a[m] = *(const bf16x8*)&As[(w * MT * 16 + m * 16 + ln) * 136 + kt * 32 + quad * 8];
#pragma unroll
            for (int nt = 0; nt < 4; nt++) {
                bf16x8 b = *(const bf16x8*)&Ws[(nt * 16 + ln) * 136 + kt * 32 + quad * 8];
#pragma unroll
                for (int m = 0; m < MT; m++)
                    acc[m][nt] = mfma16(a[m], b, acc[m][nt]);
            }
        }
    }
#pragma unroll
    for (int m = 0; m < MT; m++) {
        int rowg = r0 + w * MT * 16 + m * 16 + quad * 4;   // C row = quad*4 + reg
        if (mode == 3) {
#pragma unroll
            for (int nt = 0; nt < 4; nt++) {
                int e = n0 + nt * 16 + ln;
#pragma unroll
                for (int r = 0; r < 4; r++)
                    Of[(long)(rowg + r) * 256 + e] = acc[m][nt][r];
            }
            continue;
        }
        float scl = (mode == 1) ? SCALING : 1.0f;
#pragma unroll
        for (int nt = 0; nt < 4; nt++) {
            int e = n0 + nt * 16 + ln;
            int d = e & 31, hh = e >> 5;
#pragma unroll
            for (int r = 0; r < 4; r++) {
                int gi = rowg + r;
                int b = gi >> 10, l = gi & 1023;
                float v = acc[m][nt][r] * scl;
                float p = __shfl_xor(v, 1);   // partner col e^1, same row
                float res;
                if (mode == 2) {
                    res = v;
                } else {
                    float2 sc = tc[l * 32 + d];
                    res = v * sc.x + p * sc.y;
                }
                O[(((long)(b * 8 + hh)) * 1024 + l) * 32 + d] = f2bf(res);
            }
        }
    }
}

// ---- fused retention + LN + GELU: 128-q tile, register-P K=16 PV -------------
// R8 structure; global prefetch moved to TOP of the k-loop (distance-1) so the
// pre-barrier vmcnt(0) drain is covered by the compute phase.
__global__ __launch_bounds__(512) void attn_kernel(
    const u16* __restrict__ qr, const u16* __restrict__ kr, const u16* __restrict__ vr,
    const float* __restrict__ lng, const float* __restrict__ lnb,
    u16* __restrict__ out) {
    __shared__ __align__(16) u16 Qs[128 * 40];      // 10240 B
    __shared__ __align__(16) u16 Ks[2][64 * 40];    // 10240 B
    __shared__ __align__(16) u32 VtW[2][32 * 36];   // V^T packed dwords, 9216 B
    __shared__ float Tt[64];
    __shared__ float Ss[32];
    int b = blockIdx.z, h = blockIdx.y, q0 = blockIdx.x * 128;
    int tid = threadIdx.x, w = tid >> 6, lane = tid & 63, ln = lane & 15, quad = lane >> 4;
    long bh = b * 8 + h;
    const u16* qb = qr + bh * 32768;
    const u16* kb = kr + bh * 32768;
    const u16* vb = vr + bh * 32768;
    float dec = decay_l2(h);
    {   // stage Q (128 rows, 512 threads)
        int row = tid >> 2, seg = tid & 3;
        *(int4*)&Qs[row * 40 + seg * 8] = *(const int4*)&qb[(q0 + row) * 32 + seg * 8];
    }
    if (tid < 63) Tt[tid] = exp2f(dec * (float)tid);
    // staging duties: waves 0-3 stage K, waves 4-7 stage V
    bool isK = (tid < 256);
    int krow = (tid & 255) >> 2, kseg = tid & 3;
    int vt = tid & 255, vp = vt >> 3, vseg = vt & 7;
    int4 kreg; int2 v0, v1;
    if (isK) {
        kreg = *(const int4*)&kb[(long)krow * 32 + kseg * 8];
    } else {
        v0 = *(const int2*)&vb[(long)(vp * 2) * 32 + vseg * 4];
        v1 = *(const int2*)&vb[(long)(vp * 2 + 1) * 32 + vseg * 4];
    }
    __syncthreads();   // Qs + Tt ready
    bf16x8 aq = *(const bf16x8*)&Qs[(w * 16 + ln) * 40 + quad * 8];   // Q B-frag
    int q = q0 + w * 16 + ln;
    int q1i = q >> 5, q2i = q & 31;
    if (tid < 32) {
        float s = 0.0f;
#pragma unroll
        for (int b2 = 0; b2 < 32; b2++) s += Tt[abs(tid - b2)];
        Ss[tid] = s;
    }
    // write tile 0 to buf 0 (tile 1 is loaded at the top of iteration kt=0)
    if (isK) {
        *(int4*)&Ks[0][krow * 40 + kseg * 8] = kreg;
    } else {
        VtW[0][(vseg * 4 + 0) * 36 + vp] = __builtin_amdgcn_perm(v1.x, v0.x, 0x05040100u);
        VtW[0][(vseg * 4 + 1) * 36 + vp] = __builtin_amdgcn_perm(v1.x, v0.x, 0x07060302u);
        VtW[0][(vseg * 4 + 2) * 36 + vp] = __builtin_amdgcn_perm(v1.y, v0.y, 0x05040100u);
        VtW[0][(vseg * 4 + 3) * 36 + vp] = __builtin_amdgcn_perm(v1.y, v0.y, 0x07060302u);
    }
    __syncthreads();   // Ss + buf0 ready
    float rqv = rsqrtf(Ss[q1i] * Ss[q2i]);
    float bt[2][4];
#pragma unroll
    for (int s2 = 0; s2 < 2; s2++)
#pragma unroll
        for (int r = 0; r < 4; r++)
            bt[s2][r] = Tt[abs(q2i - (s2 * 16 + quad * 4 + r))] * rqv;   // rqv folded
    f32x4 accO0 = {}, accO1 = {};
    float den = 0.0f;
    for (int kt = 0; kt < 16; kt++) {
        int cur = kt & 1;
        // top-issue prefetch of tile kt+1: whole compute phase covers the latency
        if (kt < 15) {
            long t1 = (long)(kt + 1) * 64;
            if (isK) {
                kreg = *(const int4*)&kb[(t1 + krow) * 32 + kseg * 8];
            } else {
                v0 = *(const int2*)&vb[(t1 + vp * 2) * 32 + vseg * 4];
                v1 = *(const int2*)&vb[(t1 + vp * 2 + 1) * 32 + vseg * 4];
            }
        }
        float a0 = Tt[abs(q1i - 2 * kt)];
        float a1 = Tt[abs(q1i - 2 * kt - 1)];
        const u16* ksb = &Ks[cur][0];
        const u32* vtb = &VtW[cur][0];
#pragma unroll
        for (int nt = 0; nt < 4; nt++) {
            bf16x8 ak = *(const bf16x8*)&ksb[(nt * 16 + ln) * 40 + quad * 8];
            f32x4 s = mfma16(ak, aq, (f32x4){0.f, 0.f, 0.f, 0.f});   // S^T rows kk, col q
            float aa = (nt & 2) ? a1 : a0;
            float p0 = s[0] * aa * bt[nt & 1][0];
            float p1 = s[1] * aa * bt[nt & 1][1];
            float p2 = s[2] * aa * bt[nt & 1][2];
            float p3 = s[3] * aa * bt[nt & 1][3];
            den += fabsf(p0); den += fabsf(p1); den += fabsf(p2); den += fabsf(p3);
            // P^T fragment stays in registers: B-frag of K=16 MFMA = C-layout
            u32 blo = pack_bf16(p0, p1), bhi = pack_bf16(p2, p3);
            u64 bb = ((u64)bhi << 32) | blo;
            u64 av0 = *(const u64*)&vtb[ln * 36 + nt * 8 + quad * 2];
            u64 av1 = *(const u64*)&vtb[(16 + ln) * 36 + nt * 8 + quad * 2];
            accO0 = mfma_k16(av0, bb, accO0);   // O^T rows d=quad*4+r, col q
            accO1 = mfma_k16(av1, bb, accO1);   // d = 16 + quad*4+r
        }
        if (kt < 15) {
            int nb = 1 - cur;
            if (isK) {
                *(int4*)&Ks[nb][krow * 40 + kseg * 8] = kreg;
            } else {
                VtW[nb][(vseg * 4 + 0) * 36 + vp] = __builtin_amdgcn_perm(v1.x, v0.x, 0x05040100u);
                VtW[nb][(vseg * 4 + 1) * 36 + vp] = __builtin_amdgcn_perm(v1.x, v0.x, 0x07060302u);
                VtW[nb][(vseg * 4 + 2) * 36 + vp] = __builtin_amdgcn_perm(v1.y, v0.y, 0x05040100u);
                VtW[nb][(vseg * 4 + 3) * 36 + vp] = __builtin_amdgcn_perm(v1.y, v0.y, 0x07060302u);
            }
            __syncthreads();
        }
    }
    // reduce den over quads (lanes ln, 16+ln, 32+ln, 48+ln share col q)
    den += __shfl_xor(den, 16);
    den += __shfl_xor(den, 32);
    float id = 1.0f / fminf(fmaxf(den, 1.0f), 50000.0f);
    float o[8];
#pragma unroll
    for (int r = 0; r < 4; r++) { o[r] = accO0[r] * id; o[4 + r] = accO1[r] * id; }
    float s1 = 0.0f, s2 = 0.0f;
#pragma unroll
    for (int i = 0; i < 8; i++) { s1 += o[i]; s2 += o[i] * o[i]; }
    s1 += __shfl_xor(s1, 16); s1 += __shfl_xor(s1, 32);
    s2 += __shfl_xor(s2, 16); s2 += __shfl_xor(s2, 32);
    float mean = s1 * (1.0f / 32.0f);
    float var = s2 * (1.0f / 32.0f) - mean * mean;
    float rstd = rsqrtf(var + 1e-5f);
    float xg[8];
#pragma unroll
    for (int nv = 0; nv < 2; nv++)
#pragma unroll
        for (int r = 0; r < 4; r++) {
            int d = nv * 16 + quad * 4 + r;
            float xv = (o[nv * 4 + r] - mean) * rstd * lng[d] + lnb[d];
            xg[nv * 4 + r] = 0.5f * xv * (1.0f + erff(xv * 0.70710678118654752f));
        }
    u16* orow = out + ((long)(b * 1024 + q)) * 256 + h * 32;
    int2 st0, st1;
    st0.x = (int)pack_bf16(xg[0], xg[1]); st0.y = (int)pack_bf16(xg[2], xg[3]);
    st1.x = (int)pack_bf16(xg[4], xg[5]); st1.y = (int)pack_bf16(xg[6], xg[7]);
    *(int2*)&orow[quad * 4] = st0;
    *(int2*)&orow[16 + quad * 4] = st1;
}

extern "C" void kernel_launch(void* const* d_in, const int* in_sizes, int n_in,
                              void* d_out, int out_size, void* d_ws, size_t ws_size,
                              hipStream_t stream) {
    const float* x   = (const float*)d_in[0];
    const float* Wq  = (const float*)d_in[1];
    const float* Wk  = (const float*)d_in[2];
    const float* Wv  = (const float*)d_in[3];
    const float* Wo  = (const float*)d_in[4];
    const float* lng = (const float*)d_in[5];
    const float* lnb = (const float*)d_in[6];
    float* outp = (float*)d_out;

    u16* xb    = (u16*)d_ws;            // [B*L][256] bf16, 4 MB
    u16* wb    = xb + 2097152;          // Wq|Wk|Wv|Wo bf16, 0.5 MB
    u16* qr    = wb + 262144;           // [B][H][L][32] bf16, 4 MB
    u16* kr    = qr + 2097152;
    u16* vr    = kr + 2097152;
    u16* attnb = vr + 2097152;          // [B*L][256] bf16, 4 MB
    float2* tc = (float2*)(attnb + 2097152);   // [L][32], 256 KB

    prep_kernel<<<1280, 256, 0, stream>>>(x, Wq, Wk, Wv, Wo, xb, wb, tc);
    gemm_bt_kernel<1><<<dim3(4, 128, 3), 256, 0, stream>>>(xb, wb, tc, qr, kr, vr, nullptr, 0);
    attn_kernel<<<dim3(8, 8, 8), 512, 0, stream>>>(qr, kr, vr, lng, lnb, attnb);
    gemm_bt_kernel<1><<<dim3(4, 128, 1), 256, 0, stream>>>(attnb, wb + 3 * 65536, tc, nullptr, nullptr, nullptr, outp, 3);
}